// Round 21
// baseline (86.376 us; speedup 1.0000x reference)
//
#include <hip/hip_runtime.h>
#include <hip/hip_bf16.h>
#include <math.h>

// SE (RBF) kernel attention, bf16 MFMA flash-style, fragment-major prepack.
// score = (k2 - dist)/16 nats (q2 cancels). Unshifted weights bounded
// (p in [~0.4, ~1300], l <= ~4e5) -> no max tracking, no rescale. Shift-free
// softmax => K-split partials combine by PURE ADDITION.
// R21 = R18 (best: 256thr, 4 waves = qg x 2-way split-K, t-split halves,
// cvt_pk/permlane, score algebra in C2-scaled space) + micro-trims:
//   - 4 independent l accumulators (break the v_add dependency chains)
//   - #pragma unroll 2 on the K-tile loop (wider scheduling window)
//   - pointer-increment addressing for Kt/Vt/k2c

typedef __attribute__((ext_vector_type(8))) short bf16x8;
typedef __attribute__((ext_vector_type(4))) float f32x4;
typedef __attribute__((ext_vector_type(16))) float f32x16;
typedef __attribute__((ext_vector_type(4))) unsigned int uint32x4;
typedef __attribute__((ext_vector_type(2))) unsigned int uint32x2;

#define SEQ    2048
#define DIM    64
#define NHEAD  32
#define KVB    64
#define NKT    (SEQ / KVB)
#define TILE_B 8192        // 8 chunks x 1KB per tile (K or V)
#define C2     0.0901684403f     // log2(e)/16
#define C2SQ   0.0081303477f     // C2*C2
#define N2C2SQ -0.0162606954f    // -2*C2*C2

__device__ __forceinline__ float fast_exp2(float x) { return __builtin_amdgcn_exp2f(x); }
__device__ __forceinline__ float fast_sqrt(float x) { return __builtin_amdgcn_sqrtf(x); }

// dst = (bf16(hi) << 16) | bf16(lo), hardware RNE, single VALU inst
__device__ __forceinline__ unsigned cvt_pk_bf16(float lo, float hi) {
    unsigned r;
    asm("v_cvt_pk_bf16_f32 %0, %1, %2" : "=v"(r) : "v"(lo), "v"(hi));
    return r;
}

__device__ __forceinline__ unsigned int f2bf(float f) {
    __hip_bfloat16 h = __float2bfloat16(f);   // RNE (fallback kernel only)
    unsigned short u;
    __builtin_memcpy(&u, &h, 2);
    return (unsigned int)u;
}

__device__ __forceinline__ bf16x8 pack4(unsigned a, unsigned b, unsigned c, unsigned d) {
    uint32x4 t; t[0] = a; t[1] = b; t[2] = c; t[3] = d;
    bf16x8 r;
    __builtin_memcpy(&r, &t, 16);
    return r;
}

// ---------------- prepack: K/V -> fragment-major bf16 chunks + k2*C2 ---------
__global__ __launch_bounds__(256, 4)
void prep_kv(const float* __restrict__ Kg, const float* __restrict__ Vg,
             char* __restrict__ Kp, char* __restrict__ Vp,
             float* __restrict__ k2cg) {
    const int tid  = threadIdx.x;
    const int kt   = blockIdx.x;
    const int head = blockIdx.y;
    const size_t hb = (size_t)head * (SEQ * DIM);
    char* kdst = Kp + (size_t)(head * NKT + kt) * TILE_B;
    char* vdst = Vp + (size_t)(head * NKT + kt) * TILE_B;

    // ---- K: thread (row, sc4) covers d in [sc4*16, sc4*16+16) ----
    {
        const int row = tid >> 2;    // 0..63
        const int sc4 = tid & 3;     // s chunk
        const float* kp = Kg + hb + (size_t)(kt * KVB + row) * DIM + sc4 * 16;
        f32x4 a = *(const f32x4*)kp;
        f32x4 b = *(const f32x4*)(kp + 4);
        f32x4 c = *(const f32x4*)(kp + 8);
        f32x4 d = *(const f32x4*)(kp + 12);
        float part = 0.f;
#pragma unroll
        for (int j = 0; j < 4; ++j)
            part += a[j]*a[j] + b[j]*b[j] + c[j]*c[j] + d[j]*d[j];
        part += __shfl_xor(part, 1);
        part += __shfl_xor(part, 2);
        if (sc4 == 0) k2cg[head * SEQ + kt * KVB + row] = part * C2;

        uint32x4 w0, w1;
        w0[0] = cvt_pk_bf16(a[0], a[1]); w0[1] = cvt_pk_bf16(a[2], a[3]);
        w0[2] = cvt_pk_bf16(b[0], b[1]); w0[3] = cvt_pk_bf16(b[2], b[3]);
        w1[0] = cvt_pk_bf16(c[0], c[1]); w1[1] = cvt_pk_bf16(c[2], c[3]);
        w1[2] = cvt_pk_bf16(d[0], d[1]); w1[3] = cvt_pk_bf16(d[2], d[3]);
        const int t = row >> 5;
        char* base = kdst + (t * 4 + sc4) * 1024 + (row & 31) * 16;
        *(uint32x4*)base         = w0;   // lane = row&31      (first 8 d's)
        *(uint32x4*)(base + 512) = w1;   // lane = 32+(row&31) (second 8 d's)
    }
    // ---- V: thread (kp_=tid&31, dg=tid>>5) covers k-pair 2kp_, d in [dg*8,+8)
    {
        const int kp_ = tid & 31;
        const int dg  = tid >> 5;
        const float* vp = Vg + hb + (size_t)(kt * KVB + 2 * kp_) * DIM + dg * 8;
        f32x4 a0 = *(const f32x4*)vp;
        f32x4 a1 = *(const f32x4*)(vp + 4);
        f32x4 b0 = *(const f32x4*)(vp + DIM);
        f32x4 b1 = *(const f32x4*)(vp + DIM + 4);
        const int ks   = kp_ >> 3;
        const int lh   = (kp_ >> 2) & 1;    // lane half (l>>5)
        const int j    = kp_ & 3;           // u32 slot
#pragma unroll
        for (int e = 0; e < 8; ++e) {
            const float lo = (e < 4) ? a0[e] : a1[e - 4];
            const float hi = (e < 4) ? b0[e] : b1[e - 4];
            const unsigned pk = cvt_pk_bf16(lo, hi);
            const int d    = dg * 8 + e;
            const int half = d >> 5;
            const int l    = (d & 31) + 32 * lh;
            *(unsigned*)(vdst + (ks * 2 + half) * 1024 + l * 16 + j * 4) = pk;
        }
    }
}

// ---------------- main: split-K 32x32 MFMA flash attention, t-split ----------
// 4 waves: wave w = (qgroup w&1, khalf w>>1). Each sweeps 16 K-tiles x 32 q.
__global__ __launch_bounds__(256, 3)
void se_attn_main(const float* __restrict__ Qg, const char* __restrict__ Kp,
                  const char* __restrict__ Vp, const float* __restrict__ k2cg,
                  float* __restrict__ Og) {
    __shared__ char  Osh[2][8192];     // partial O, [qg][d 64][q 32] f32, swz
    __shared__ float lsp[2][32];       // partial l from K-half 1
    __shared__ float linv_sh[2][32];

    const int tid = threadIdx.x;
    const int w   = tid >> 6;          // wave 0..3
    const int qg  = w & 1;             // q-group
    const int kh  = w >> 1;            // K-half
    const int l   = tid & 63;
    const int ql  = l & 31;            // q col (QK) / d col (PV)
    const int hi  = l >> 5;

    // bijective XCD swizzle: 1024 blocks -> each XCD gets 4 contiguous heads
    const int bid  = blockIdx.x;                 // 0..1023
    const int wg   = (bid & 7) * 128 + (bid >> 3);
    const int head = wg >> 5;
    const int qb   = wg & 31;

    const size_t hb = (size_t)head * (SEQ * DIM);
    const int qbase = qb * 64 + qg * 32;

    // ---- Q B-fragments: qf[s] = Q[qbase+ql][s*16 + hi*8 .. +7]; q2 ----
    bf16x8 qf[4];
    float q2 = 0.f;
#pragma unroll
    for (int s = 0; s < 4; ++s) {
        const float* qp = Qg + hb + (size_t)(qbase + ql) * DIM + s * 16 + hi * 8;
        f32x4 a = *(const f32x4*)qp;
        f32x4 b = *(const f32x4*)(qp + 4);
#pragma unroll
        for (int j = 0; j < 4; ++j) q2 += a[j] * a[j] + b[j] * b[j];
        uint32x4 qw;
        qw[0] = cvt_pk_bf16(a[0], a[1]); qw[1] = cvt_pk_bf16(a[2], a[3]);
        qw[2] = cvt_pk_bf16(b[0], b[1]); qw[3] = cvt_pk_bf16(b[2], b[3]);
        __builtin_memcpy(&qf[s], &qw, 16);
    }
    q2 += __shfl_xor(q2, 32);          // partner lane holds the other 32 d's
    const float q2c = q2 * C2SQ;       // C2^2 * q2

    f32x16 z16;                        // persistent zero C-operand
#pragma unroll
    for (int i = 0; i < 16; ++i) z16[i] = 0.f;
    f32x16 o0 = z16, o1 = z16;
    float ls0 = 0.f, ls1 = 0.f, ls2 = 0.f, ls3 = 0.f;   // 4 indep chains

    const int loff = l * 16;

    // pointer-increment addressing: start of this wave's K-half
    const char*  Kt  = Kp   + ((size_t)head * NKT + kh * (NKT / 2)) * TILE_B;
    const char*  Vt  = Vp   + ((size_t)head * NKT + kh * (NKT / 2)) * TILE_B;
    const float* kcp = k2cg + head * SEQ + kh * (SEQ / 2);

#pragma unroll 2
    for (int i = 0; i < NKT / 2; ++i) {
#pragma unroll
        for (int t = 0; t < 2; ++t) {
            // k2c quads for this half: k = t*32 + rq*8 + 4*hi + (0..3)
            f32x4 kcq[4];
#pragma unroll
            for (int rq = 0; rq < 4; ++rq)
                kcq[rq] = *(const f32x4*)(kcp + t * 32 + rq * 8 + 4 * hi);

            // ---- QK^T (this half): first MFMA consumes z16 ----
            f32x16 st;
            __builtin_amdgcn_s_setprio(1);
            {
                bf16x8 kf = *(const bf16x8*)(Kt + (t * 4 + 0) * 1024 + loff);
                st = __builtin_amdgcn_mfma_f32_32x32x16_bf16(kf, qf[0], z16, 0, 0, 0);
            }
#pragma unroll
            for (int s = 1; s < 4; ++s) {
                bf16x8 kf = *(const bf16x8*)(Kt + (t * 4 + s) * 1024 + loff);
                st = __builtin_amdgcn_mfma_f32_32x32x16_bf16(kf, qf[s], st, 0, 0, 0);
            }
            __builtin_amdgcn_s_setprio(0);

            // ---- V fragments for this half (ks = 2t, 2t+1) issued early ----
            bf16x8 vfa0 = *(const bf16x8*)(Vt + ((2 * t + 0) * 2 + 0) * 1024 + loff);
            bf16x8 vfa1 = *(const bf16x8*)(Vt + ((2 * t + 0) * 2 + 1) * 1024 + loff);
            bf16x8 vfb0 = *(const bf16x8*)(Vt + ((2 * t + 1) * 2 + 0) * 1024 + loff);
            bf16x8 vfb1 = *(const bf16x8*)(Vt + ((2 * t + 1) * 2 + 1) * 1024 + loff);

            // ---- scores: p = exp2(k2c - sqrt(|C2^2*sq|)), 3 VALU + 2 trans --
            unsigned cpk[4][2];
#pragma unroll
            for (int rq = 0; rq < 4; ++rq) {
                float pv[4];
#pragma unroll
                for (int r = 0; r < 4; ++r) {
                    const float dot = st[rq * 4 + r];
                    const float kkc = kcq[rq][r];
                    const float t1  = fmaf(kkc, C2, q2c);       // C2^2(q2+k2)
                    const float sqC = fmaf(N2C2SQ, dot, t1);    // C2^2*sq
                    pv[r] = fast_exp2(kkc - fast_sqrt(fabsf(sqC)));
                }
                ls0 += pv[0]; ls1 += pv[1]; ls2 += pv[2]; ls3 += pv[3];
                cpk[rq][0] = cvt_pk_bf16(pv[0], pv[1]);
                cpk[rq][1] = cvt_pk_bf16(pv[2], pv[3]);
            }

            // ---- P redistribution: 2-arg permlane, no selects ----
            bf16x8 pa[2];
#pragma unroll
            for (int e = 0; e < 2; ++e) {
                uint32x2 ra = __builtin_amdgcn_permlane32_swap(
                    cpk[2 * e + 0][0], cpk[2 * e + 1][0], false, false);
                uint32x2 rb = __builtin_amdgcn_permlane32_swap(
                    cpk[2 * e + 0][1], cpk[2 * e + 1][1], false, false);
                pa[e] = pack4(ra[0], rb[0], ra[1], rb[1]);
            }

            // ---- PV (this half): o += P[32q x 32k] . V[32k x 64d] ----
            __builtin_amdgcn_s_setprio(1);
            o0 = __builtin_amdgcn_mfma_f32_32x32x16_bf16(pa[0], vfa0, o0, 0, 0, 0);
            o1 = __builtin_amdgcn_mfma_f32_32x32x16_bf16(pa[0], vfa1, o1, 0, 0, 0);
            o0 = __builtin_amdgcn_mfma_f32_32x32x16_bf16(pa[1], vfb0, o0, 0, 0, 0);
            o1 = __builtin_amdgcn_mfma_f32_32x32x16_bf16(pa[1], vfb1, o1, 0, 0, 0);
            __builtin_amdgcn_s_setprio(0);
        }
        Kt  += TILE_B;
        Vt  += TILE_B;
        kcp += KVB;
    }

    // ---- combine K-halves: half-1 writes partials to LDS, half-0 reduces ----
    float ls = (ls0 + ls1) + (ls2 + ls3);
    ls += __shfl_xor(ls, 32);          // total over this wave's K-half

    const int swz = (ql & 7) << 4;     // d-row XOR swizzle
    char* Oq = Osh[qg];

    if (kh == 1) {
#pragma unroll
        for (int qd = 0; qd < 4; ++qd) {
            const int off = ((8 * qd + 4 * hi) * 4) ^ swz;
            f32x4 v0, v1;
#pragma unroll
            for (int r = 0; r < 4; ++r) { v0[r] = o0[4 * qd + r]; v1[r] = o1[4 * qd + r]; }
            *(f32x4*)(Oq + ql * 128 + off)        = v0;   // d = ql
            *(f32x4*)(Oq + (32 + ql) * 128 + off) = v1;   // d = 32+ql
        }
        if (hi == 0) lsp[qg][ql] = ls;
    }
    __syncthreads();
    if (kh == 0) {
        ls += lsp[qg][ql];
        const float inv = 1.f / ls;
        if (hi == 0) linv_sh[qg][ql] = inv;   // same-wave LDS, ordered
#pragma unroll
        for (int qd = 0; qd < 4; ++qd) {
            const int off = ((8 * qd + 4 * hi) * 4) ^ swz;
            f32x4 v0 = *(const f32x4*)(Oq + ql * 128 + off);
            f32x4 v1 = *(const f32x4*)(Oq + (32 + ql) * 128 + off);
#pragma unroll
            for (int r = 0; r < 4; ++r) { o0[4 * qd + r] += v0[r]; o1[4 * qd + r] += v1[r]; }
        }
        f32x4 iq[4];
#pragma unroll
        for (int rq = 0; rq < 4; ++rq)
            iq[rq] = *(const f32x4*)(&linv_sh[qg][rq * 8 + 4 * hi]);
#pragma unroll
        for (int reg = 0; reg < 16; ++reg) {
            const int qloc = (reg & 3) + 8 * (reg >> 2) + 4 * hi;
            float* orow = Og + hb + (size_t)(qbase + qloc) * DIM;
            const float s = iq[reg >> 2][reg & 3];
            orow[ql]      = o0[reg] * s;     // d = ql
            orow[32 + ql] = o1[reg] * s;     // d = 32 + ql
        }
    }
}

// ---------------- fallback (no-workspace monolithic, R2 kernel) --------------
__global__ __launch_bounds__(256, 4)
void se_attn_mfma(const float* __restrict__ Qg, const float* __restrict__ Kg,
                  const float* __restrict__ Vg, float* __restrict__ Og) {
    __shared__ char  Kl[KVB * 128];
    __shared__ char  Vt[DIM * 128];
    __shared__ char  Pl[4][16 * 128];
    __shared__ float k2s[KVB];

    const int tid = threadIdx.x;
    const int w   = tid >> 6;
    const int l   = tid & 63;
    const int lq  = l & 15;
    const int g   = l >> 4;
    const size_t hb = (size_t)blockIdx.y * (SEQ * DIM);
    const int q = blockIdx.x * 64 + w * 16 + lq;
    char* Pw = Pl[w];
    const int swq = (lq & 7) << 4;

    bf16x8 qf[2];
    float q2 = 0.f;
#pragma unroll
    for (int h = 0; h < 2; ++h) {
        const float* qp = Qg + hb + (size_t)q * DIM + h * 32 + g * 8;
        f32x4 a = *(const f32x4*)qp;
        f32x4 b = *(const f32x4*)(qp + 4);
#pragma unroll
        for (int j = 0; j < 4; ++j) {
            q2 += a[j] * a[j] + b[j] * b[j];
            qf[h][j]     = (short)f2bf(a[j]);
            qf[h][4 + j] = (short)f2bf(b[j]);
        }
    }
    q2 += __shfl_xor(q2, 16);
    q2 += __shfl_xor(q2, 32);

    f32x4 ofr[4];
#pragma unroll
    for (int i = 0; i < 4; ++i) ofr[i] = (f32x4){0.f, 0.f, 0.f, 0.f};
    float m = -INFINITY, lsum = 0.f;

    const int srow = tid >> 2;
    const int sc4  = tid & 3;
    const int vpr  = tid & 31;
    const int vd0  = (tid >> 5) * 8;

    for (int kt = 0; kt < NKT; ++kt) {
        __syncthreads();
        {
            const float* kp = Kg + hb + (size_t)(kt * KVB + srow) * DIM + sc4 * 16;
            f32x4 a = *(const f32x4*)kp;
            f32x4 b = *(const f32x4*)(kp + 4);
            f32x4 c = *(const f32x4*)(kp + 8);
            f32x4 d = *(const f32x4*)(kp + 12);
            float part = 0.f;
#pragma unroll
            for (int j = 0; j < 4; ++j)
                part += a[j]*a[j] + b[j]*b[j] + c[j]*c[j] + d[j]*d[j];
            part += __shfl_xor(part, 1);
            part += __shfl_xor(part, 2);
            if (sc4 == 0) k2s[srow] = part;
            bf16x8 p0, p1;
#pragma unroll
            for (int j = 0; j < 4; ++j) {
                p0[j]     = (short)f2bf(a[j]);
                p0[4 + j] = (short)f2bf(b[j]);
                p1[j]     = (short)f2bf(c[j]);
                p1[4 + j] = (short)f2bf(d[j]);
            }
            const int sw = (srow & 7) << 4;
            const int wa = srow * 128 + sc4 * 32;
            *(bf16x8*)(Kl + (wa ^ sw))        = p0;
            *(bf16x8*)(Kl + ((wa + 16) ^ sw)) = p1;
        }
        {
            const float* vp = Vg + hb + (size_t)(kt * KVB + 2 * vpr) * DIM + vd0;
            f32x4 a0 = *(const f32x4*)vp;
            f32x4 a1 = *(const f32x4*)(vp + 4);
            f32x4 b0 = *(const f32x4*)(vp + DIM);
            f32x4 b1 = *(const f32x4*)(vp + DIM + 4);
#pragma unroll
            for (int j = 0; j < 8; ++j) {
                const float lo = (j < 4) ? a0[j] : a1[j - 4];
                const float hi2 = (j < 4) ? b0[j] : b1[j - 4];
                const unsigned int pk = f2bf(lo) | (f2bf(hi2) << 16);
                const int d = vd0 + j;
                const int wa = d * 128 + vpr * 4;
                *(unsigned int*)(Vt + (wa ^ ((d & 7) << 4))) = pk;
            }
        }
        __syncthreads();

        f32x4 st[4];
#pragma unroll
        for (int f = 0; f < 4; ++f) st[f] = (f32x4){0.f, 0.f, 0.f, 0.f};
#pragma unroll
        for (int f = 0; f < 4; ++f) {
#pragma unroll
            for (int h = 0; h < 2; ++h) {
                const int ra = (f * 16 + lq) * 128 + h * 64 + g * 16;
                bf16x8 kf = *(const bf16x8*)(Kl + (ra ^ swq));
                st[f] = __builtin_amdgcn_mfma_f32_16x16x32_bf16(kf, qf[h], st[f], 0, 0, 0);
            }
        }

        float sc[4][4];
        float tmax = -INFINITY;
#pragma unroll
        for (int f = 0; f < 4; ++f) {
            const f32x4 k2v = *(const f32x4*)(k2s + f * 16 + g * 4);
#pragma unroll
            for (int r = 0; r < 4; ++r) {
                const float kk = k2v[r];
                const float sq = fmaxf(fmaf(-2.f, st[f][r], q2 + kk), 0.f);
                const float s  = (kk - sqrtf(sq)) * 0.0625f;
                sc[f][r] = s;
                tmax = fmaxf(tmax, s);
            }
        }
        tmax = fmaxf(tmax, __shfl_xor(tmax, 16));
        tmax = fmaxf(tmax, __shfl_xor(tmax, 32));
        const float nm    = fmaxf(m, tmax);
        const float scale = __expf(m - nm);
        m = nm;
        lsum *= scale;
#pragma unroll
        for (int i = 0; i < 4; ++i) {
            ofr[i][0] *= scale; ofr[i][1] *= scale;
            ofr[i][2] *= scale; ofr[i][3] *= scale;
        }
#pragma unroll
        for (int f = 0; f < 4; ++f) {
#pragma unroll
            for (int e = 0; e < 2; ++e) {
                const float p0 = __expf(sc[f][2 * e]     - m);
                const float p1 = __expf(sc[f][2 * e + 1] - m);
                lsum += p0 + p1;
                const unsigned int pk = f2bf(p0) | (f2bf(p1) << 16);
                const int pr = 8 * f + 2 * g + e;
                const int wa = lq * 128 + pr * 4;
                *(unsigned int*)(Pw + (wa ^ swq)) = pk;
            }
        }

        bf16x8 pf[2];
#pragma unroll
        for (int h = 0; h < 2; ++h) {
            const int ra = lq * 128 + h * 64 + g * 16;
            pf[h] = *(const bf16x8*)(Pw + (ra ^ swq));
        }
#pragma unroll
        for (int db = 0; db < 4; ++db) {
#pragma unroll
            for (int h = 0; h < 2; ++h) {
                const int ra = (db * 16 + lq) * 128 + h * 64 + g * 16;
                bf16x8 vf = *(const bf16x8*)(Vt + (ra ^ swq));
                ofr[db] = __builtin_amdgcn_mfma_f32_16x16x32_bf16(vf, pf[h], ofr[db], 0, 0, 0);
            }
        }
    }

    lsum += __shfl_xor(lsum, 16);
    lsum += __shfl_xor(lsum, 32);
    const float inv = 1.f / lsum;
    float* op = Og + hb + (size_t)q * DIM;
#pragma unroll
    for (int db = 0; db < 4; ++db) {
#pragma unroll
        for (int r = 0; r < 4; ++r) {
            op[db * 16 + g * 4 + r] = ofr[db][r] * inv;
        }
    }
}

extern "C" void kernel_launch(void* const* d_in, const int* in_sizes, int n_in,
                              void* d_out, int out_size, void* d_ws, size_t ws_size,
                              hipStream_t stream) {
    const float* Q = (const float*)d_in[0];
    const float* K = (const float*)d_in[1];
    const float* V = (const float*)d_in[2];
    float* O = (float*)d_out;

    const size_t KP_B = (size_t)NHEAD * NKT * TILE_B;    // 8 MB
    const size_t K2_B = (size_t)NHEAD * SEQ * 4;         // 256 KB
    const size_t need = 2 * KP_B + K2_B;

    if (ws_size >= need) {
        char*  Kp  = (char*)d_ws;
        char*  Vp  = Kp + KP_B;
        float* k2c = (float*)(Kp + 2 * KP_B);
        prep_kv<<<dim3(NKT, NHEAD), 256, 0, stream>>>(K, V, Kp, Vp, k2c);
        se_attn_main<<<dim3((SEQ / 64) * NHEAD), 256, 0, stream>>>(Q, Kp, Vp, k2c, O);
    } else {
        se_attn_mfma<<<dim3(SEQ / 64, NHEAD), 256, 0, stream>>>(Q, K, V, O);
    }
}

// Round 22
// 80.076 us; speedup vs baseline: 1.0787x; 1.0787x over previous
//
#include <hip/hip_runtime.h>
#include <hip/hip_bf16.h>
#include <math.h>

// SE (RBF) kernel attention, bf16 MFMA flash-style, fragment-major prepack.
// score = (k2 - dist)/16 nats (q2 cancels). Unshifted weights bounded
// (p in [~0.4, ~1300], l <= ~4e5) -> no max tracking, no rescale. Shift-free
// softmax => K-split partials combine by PURE ADDITION.
// R22 = exact revert to R18 (best verified: main 72.4us): 256thr, 4 waves =
// qg x 2-way split-K, t-split 32-key halves, cvt_pk/permlane P path, score
// algebra in C2-scaled space. R19-R21 established this is the practical
// floor for this decomposition (occupancy-insensitive, compiler-schedule
// near-optimal; all further source-level interventions regressed).

typedef __attribute__((ext_vector_type(8))) short bf16x8;
typedef __attribute__((ext_vector_type(4))) float f32x4;
typedef __attribute__((ext_vector_type(16))) float f32x16;
typedef __attribute__((ext_vector_type(4))) unsigned int uint32x4;
typedef __attribute__((ext_vector_type(2))) unsigned int uint32x2;

#define SEQ    2048
#define DIM    64
#define NHEAD  32
#define KVB    64
#define NKT    (SEQ / KVB)
#define TILE_B 8192        // 8 chunks x 1KB per tile (K or V)
#define C2     0.0901684403f     // log2(e)/16
#define C2SQ   0.0081303477f     // C2*C2
#define N2C2SQ -0.0162606954f    // -2*C2*C2

__device__ __forceinline__ float fast_exp2(float x) { return __builtin_amdgcn_exp2f(x); }
__device__ __forceinline__ float fast_sqrt(float x) { return __builtin_amdgcn_sqrtf(x); }

// dst = (bf16(hi) << 16) | bf16(lo), hardware RNE, single VALU inst
__device__ __forceinline__ unsigned cvt_pk_bf16(float lo, float hi) {
    unsigned r;
    asm("v_cvt_pk_bf16_f32 %0, %1, %2" : "=v"(r) : "v"(lo), "v"(hi));
    return r;
}

__device__ __forceinline__ unsigned int f2bf(float f) {
    __hip_bfloat16 h = __float2bfloat16(f);   // RNE (fallback kernel only)
    unsigned short u;
    __builtin_memcpy(&u, &h, 2);
    return (unsigned int)u;
}

__device__ __forceinline__ bf16x8 pack4(unsigned a, unsigned b, unsigned c, unsigned d) {
    uint32x4 t; t[0] = a; t[1] = b; t[2] = c; t[3] = d;
    bf16x8 r;
    __builtin_memcpy(&r, &t, 16);
    return r;
}

// ---------------- prepack: K/V -> fragment-major bf16 chunks + k2*C2 ---------
// K chunk (t,s): lane l holds K[kt*64 + t*32 + (l&31)][s*16 + (l>>5)*8 .. +8]
// V chunk (ks,half): lane l holds pairs (V[k][d],V[k+1][d]) packed as u32,
//   d = half*32 + (l&31), k = ks*16 + (l>>5)*8 + 2j  (j=0..3)
__global__ __launch_bounds__(256, 4)
void prep_kv(const float* __restrict__ Kg, const float* __restrict__ Vg,
             char* __restrict__ Kp, char* __restrict__ Vp,
             float* __restrict__ k2cg) {
    const int tid  = threadIdx.x;
    const int kt   = blockIdx.x;
    const int head = blockIdx.y;
    const size_t hb = (size_t)head * (SEQ * DIM);
    char* kdst = Kp + (size_t)(head * NKT + kt) * TILE_B;
    char* vdst = Vp + (size_t)(head * NKT + kt) * TILE_B;

    // ---- K: thread (row, sc4) covers d in [sc4*16, sc4*16+16) ----
    {
        const int row = tid >> 2;    // 0..63
        const int sc4 = tid & 3;     // s chunk
        const float* kp = Kg + hb + (size_t)(kt * KVB + row) * DIM + sc4 * 16;
        f32x4 a = *(const f32x4*)kp;
        f32x4 b = *(const f32x4*)(kp + 4);
        f32x4 c = *(const f32x4*)(kp + 8);
        f32x4 d = *(const f32x4*)(kp + 12);
        float part = 0.f;
#pragma unroll
        for (int j = 0; j < 4; ++j)
            part += a[j]*a[j] + b[j]*b[j] + c[j]*c[j] + d[j]*d[j];
        part += __shfl_xor(part, 1);
        part += __shfl_xor(part, 2);
        if (sc4 == 0) k2cg[head * SEQ + kt * KVB + row] = part * C2;

        uint32x4 w0, w1;
        w0[0] = cvt_pk_bf16(a[0], a[1]); w0[1] = cvt_pk_bf16(a[2], a[3]);
        w0[2] = cvt_pk_bf16(b[0], b[1]); w0[3] = cvt_pk_bf16(b[2], b[3]);
        w1[0] = cvt_pk_bf16(c[0], c[1]); w1[1] = cvt_pk_bf16(c[2], c[3]);
        w1[2] = cvt_pk_bf16(d[0], d[1]); w1[3] = cvt_pk_bf16(d[2], d[3]);
        const int t = row >> 5;
        char* base = kdst + (t * 4 + sc4) * 1024 + (row & 31) * 16;
        *(uint32x4*)base         = w0;   // lane = row&31      (first 8 d's)
        *(uint32x4*)(base + 512) = w1;   // lane = 32+(row&31) (second 8 d's)
    }
    // ---- V: thread (kp_=tid&31, dg=tid>>5) covers k-pair 2kp_, d in [dg*8,+8)
    {
        const int kp_ = tid & 31;
        const int dg  = tid >> 5;
        const float* vp = Vg + hb + (size_t)(kt * KVB + 2 * kp_) * DIM + dg * 8;
        f32x4 a0 = *(const f32x4*)vp;
        f32x4 a1 = *(const f32x4*)(vp + 4);
        f32x4 b0 = *(const f32x4*)(vp + DIM);
        f32x4 b1 = *(const f32x4*)(vp + DIM + 4);
        const int ks   = kp_ >> 3;
        const int lh   = (kp_ >> 2) & 1;    // lane half (l>>5)
        const int j    = kp_ & 3;           // u32 slot
#pragma unroll
        for (int e = 0; e < 8; ++e) {
            const float lo = (e < 4) ? a0[e] : a1[e - 4];
            const float hi = (e < 4) ? b0[e] : b1[e - 4];
            const unsigned pk = cvt_pk_bf16(lo, hi);
            const int d    = dg * 8 + e;
            const int half = d >> 5;
            const int l    = (d & 31) + 32 * lh;
            *(unsigned*)(vdst + (ks * 2 + half) * 1024 + l * 16 + j * 4) = pk;
        }
    }
}

// ---------------- main: split-K 32x32 MFMA flash attention, t-split ----------
// 4 waves: wave w = (qgroup w&1, khalf w>>1). Each sweeps 16 K-tiles x 32 q.
// Each tile processed as two serial 32-key halves to keep transient regs low.
__global__ __launch_bounds__(256, 3)
void se_attn_main(const float* __restrict__ Qg, const char* __restrict__ Kp,
                  const char* __restrict__ Vp, const float* __restrict__ k2cg,
                  float* __restrict__ Og) {
    __shared__ char  Osh[2][8192];     // partial O, [qg][d 64][q 32] f32, swz
    __shared__ float lsp[2][32];       // partial l from K-half 1
    __shared__ float linv_sh[2][32];

    const int tid = threadIdx.x;
    const int w   = tid >> 6;          // wave 0..3
    const int qg  = w & 1;             // q-group
    const int kh  = w >> 1;            // K-half
    const int l   = tid & 63;
    const int ql  = l & 31;            // q col (QK) / d col (PV)
    const int hi  = l >> 5;

    // bijective XCD swizzle: 1024 blocks -> each XCD gets 4 contiguous heads
    const int bid  = blockIdx.x;                 // 0..1023
    const int wg   = (bid & 7) * 128 + (bid >> 3);
    const int head = wg >> 5;
    const int qb   = wg & 31;

    const size_t hb = (size_t)head * (SEQ * DIM);
    const int qbase = qb * 64 + qg * 32;

    const char*  Kph  = Kp + (size_t)head * NKT * TILE_B;
    const char*  Vph  = Vp + (size_t)head * NKT * TILE_B;
    const float* k2ch = k2cg + head * SEQ;

    // ---- Q B-fragments: qf[s] = Q[qbase+ql][s*16 + hi*8 .. +7]; q2 ----
    bf16x8 qf[4];
    float q2 = 0.f;
#pragma unroll
    for (int s = 0; s < 4; ++s) {
        const float* qp = Qg + hb + (size_t)(qbase + ql) * DIM + s * 16 + hi * 8;
        f32x4 a = *(const f32x4*)qp;
        f32x4 b = *(const f32x4*)(qp + 4);
#pragma unroll
        for (int j = 0; j < 4; ++j) q2 += a[j] * a[j] + b[j] * b[j];
        uint32x4 qw;
        qw[0] = cvt_pk_bf16(a[0], a[1]); qw[1] = cvt_pk_bf16(a[2], a[3]);
        qw[2] = cvt_pk_bf16(b[0], b[1]); qw[3] = cvt_pk_bf16(b[2], b[3]);
        __builtin_memcpy(&qf[s], &qw, 16);
    }
    q2 += __shfl_xor(q2, 32);          // partner lane holds the other 32 d's
    const float q2c = q2 * C2SQ;       // C2^2 * q2

    f32x16 z16;                        // persistent zero C-operand
#pragma unroll
    for (int i = 0; i < 16; ++i) z16[i] = 0.f;
    f32x16 o0 = z16, o1 = z16;
    float lsA = 0.f, lsB = 0.f;

    const int loff = l * 16;

    for (int i = 0; i < NKT / 2; ++i) {
        const int kt = kh * (NKT / 2) + i;
        const char* Kt = Kph + (size_t)kt * TILE_B;
        const char* Vt = Vph + (size_t)kt * TILE_B;

#pragma unroll
        for (int t = 0; t < 2; ++t) {
            // k2c quads for this half: k = kt*64 + t*32 + rq*8 + 4*hi + (0..3)
            f32x4 kcq[4];
#pragma unroll
            for (int rq = 0; rq < 4; ++rq)
                kcq[rq] = *(const f32x4*)(k2ch + kt * 64 + t * 32 + rq * 8 + 4 * hi);

            // ---- QK^T (this half): first MFMA consumes z16 ----
            f32x16 st;
            __builtin_amdgcn_s_setprio(1);
            {
                bf16x8 kf = *(const bf16x8*)(Kt + (t * 4 + 0) * 1024 + loff);
                st = __builtin_amdgcn_mfma_f32_32x32x16_bf16(kf, qf[0], z16, 0, 0, 0);
            }
#pragma unroll
            for (int s = 1; s < 4; ++s) {
                bf16x8 kf = *(const bf16x8*)(Kt + (t * 4 + s) * 1024 + loff);
                st = __builtin_amdgcn_mfma_f32_32x32x16_bf16(kf, qf[s], st, 0, 0, 0);
            }
            __builtin_amdgcn_s_setprio(0);

            // ---- V fragments for this half (ks = 2t, 2t+1) issued early ----
            bf16x8 vfa0 = *(const bf16x8*)(Vt + ((2 * t + 0) * 2 + 0) * 1024 + loff);
            bf16x8 vfa1 = *(const bf16x8*)(Vt + ((2 * t + 0) * 2 + 1) * 1024 + loff);
            bf16x8 vfb0 = *(const bf16x8*)(Vt + ((2 * t + 1) * 2 + 0) * 1024 + loff);
            bf16x8 vfb1 = *(const bf16x8*)(Vt + ((2 * t + 1) * 2 + 1) * 1024 + loff);

            // ---- scores: p = exp2(k2c - sqrt(|C2^2*sq|)), 3 VALU + 2 trans --
            unsigned cpk[4][2];
#pragma unroll
            for (int rq = 0; rq < 4; ++rq) {
                float pv[4];
#pragma unroll
                for (int r = 0; r < 4; ++r) {
                    const float dot = st[rq * 4 + r];
                    const float kkc = kcq[rq][r];
                    const float t1  = fmaf(kkc, C2, q2c);       // C2^2(q2+k2)
                    const float sqC = fmaf(N2C2SQ, dot, t1);    // C2^2*sq
                    const float p   = fast_exp2(kkc - fast_sqrt(fabsf(sqC)));
                    if (r & 1) lsB += p; else lsA += p;
                    pv[r] = p;
                }
                cpk[rq][0] = cvt_pk_bf16(pv[0], pv[1]);
                cpk[rq][1] = cvt_pk_bf16(pv[2], pv[3]);
            }

            // ---- P redistribution: 2-arg permlane, no selects ----
            bf16x8 pa[2];
#pragma unroll
            for (int e = 0; e < 2; ++e) {
                uint32x2 ra = __builtin_amdgcn_permlane32_swap(
                    cpk[2 * e + 0][0], cpk[2 * e + 1][0], false, false);
                uint32x2 rb = __builtin_amdgcn_permlane32_swap(
                    cpk[2 * e + 0][1], cpk[2 * e + 1][1], false, false);
                pa[e] = pack4(ra[0], rb[0], ra[1], rb[1]);
            }

            // ---- PV (this half): o += P[32q x 32k] . V[32k x 64d] ----
            __builtin_amdgcn_s_setprio(1);
            o0 = __builtin_amdgcn_mfma_f32_32x32x16_bf16(pa[0], vfa0, o0, 0, 0, 0);
            o1 = __builtin_amdgcn_mfma_f32_32x32x16_bf16(pa[0], vfa1, o1, 0, 0, 0);
            o0 = __builtin_amdgcn_mfma_f32_32x32x16_bf16(pa[1], vfb0, o0, 0, 0, 0);
            o1 = __builtin_amdgcn_mfma_f32_32x32x16_bf16(pa[1], vfb1, o1, 0, 0, 0);
            __builtin_amdgcn_s_setprio(0);
        }
    }

    // ---- combine K-halves: half-1 writes partials to LDS, half-0 reduces ----
    float ls = lsA + lsB;
    ls += __shfl_xor(ls, 32);          // total over this wave's K-half

    const int swz = (ql & 7) << 4;     // d-row XOR swizzle
    char* Oq = Osh[qg];

    if (kh == 1) {
#pragma unroll
        for (int qd = 0; qd < 4; ++qd) {
            const int off = ((8 * qd + 4 * hi) * 4) ^ swz;
            f32x4 v0, v1;
#pragma unroll
            for (int r = 0; r < 4; ++r) { v0[r] = o0[4 * qd + r]; v1[r] = o1[4 * qd + r]; }
            *(f32x4*)(Oq + ql * 128 + off)        = v0;   // d = ql
            *(f32x4*)(Oq + (32 + ql) * 128 + off) = v1;   // d = 32+ql
        }
        if (hi == 0) lsp[qg][ql] = ls;
    }
    __syncthreads();
    if (kh == 0) {
        ls += lsp[qg][ql];
        const float inv = 1.f / ls;
        if (hi == 0) linv_sh[qg][ql] = inv;   // same-wave LDS, ordered
#pragma unroll
        for (int qd = 0; qd < 4; ++qd) {
            const int off = ((8 * qd + 4 * hi) * 4) ^ swz;
            f32x4 v0 = *(const f32x4*)(Oq + ql * 128 + off);
            f32x4 v1 = *(const f32x4*)(Oq + (32 + ql) * 128 + off);
#pragma unroll
            for (int r = 0; r < 4; ++r) { o0[4 * qd + r] += v0[r]; o1[4 * qd + r] += v1[r]; }
        }
        f32x4 iq[4];
#pragma unroll
        for (int rq = 0; rq < 4; ++rq)
            iq[rq] = *(const f32x4*)(&linv_sh[qg][rq * 8 + 4 * hi]);
#pragma unroll
        for (int reg = 0; reg < 16; ++reg) {
            const int qloc = (reg & 3) + 8 * (reg >> 2) + 4 * hi;
            float* orow = Og + hb + (size_t)(qbase + qloc) * DIM;
            const float s = iq[reg >> 2][reg & 3];
            orow[ql]      = o0[reg] * s;     // d = ql
            orow[32 + ql] = o1[reg] * s;     // d = 32 + ql
        }
    }
}

// ---------------- fallback (no-workspace monolithic, R2 kernel) --------------
__global__ __launch_bounds__(256, 4)
void se_attn_mfma(const float* __restrict__ Qg, const float* __restrict__ Kg,
                  const float* __restrict__ Vg, float* __restrict__ Og) {
    __shared__ char  Kl[KVB * 128];
    __shared__ char  Vt[DIM * 128];
    __shared__ char  Pl[4][16 * 128];
    __shared__ float k2s[KVB];

    const int tid = threadIdx.x;
    const int w   = tid >> 6;
    const int l   = tid & 63;
    const int lq  = l & 15;
    const int g   = l >> 4;
    const size_t hb = (size_t)blockIdx.y * (SEQ * DIM);
    const int q = blockIdx.x * 64 + w * 16 + lq;
    char* Pw = Pl[w];
    const int swq = (lq & 7) << 4;

    bf16x8 qf[2];
    float q2 = 0.f;
#pragma unroll
    for (int h = 0; h < 2; ++h) {
        const float* qp = Qg + hb + (size_t)q * DIM + h * 32 + g * 8;
        f32x4 a = *(const f32x4*)qp;
        f32x4 b = *(const f32x4*)(qp + 4);
#pragma unroll
        for (int j = 0; j < 4; ++j) {
            q2 += a[j] * a[j] + b[j] * b[j];
            qf[h][j]     = (short)f2bf(a[j]);
            qf[h][4 + j] = (short)f2bf(b[j]);
        }
    }
    q2 += __shfl_xor(q2, 16);
    q2 += __shfl_xor(q2, 32);

    f32x4 ofr[4];
#pragma unroll
    for (int i = 0; i < 4; ++i) ofr[i] = (f32x4){0.f, 0.f, 0.f, 0.f};
    float m = -INFINITY, lsum = 0.f;

    const int srow = tid >> 2;
    const int sc4  = tid & 3;
    const int vpr  = tid & 31;
    const int vd0  = (tid >> 5) * 8;

    for (int kt = 0; kt < NKT; ++kt) {
        __syncthreads();
        {
            const float* kp = Kg + hb + (size_t)(kt * KVB + srow) * DIM + sc4 * 16;
            f32x4 a = *(const f32x4*)kp;
            f32x4 b = *(const f32x4*)(kp + 4);
            f32x4 c = *(const f32x4*)(kp + 8);
            f32x4 d = *(const f32x4*)(kp + 12);
            float part = 0.f;
#pragma unroll
            for (int j = 0; j < 4; ++j)
                part += a[j]*a[j] + b[j]*b[j] + c[j]*c[j] + d[j]*d[j];
            part += __shfl_xor(part, 1);
            part += __shfl_xor(part, 2);
            if (sc4 == 0) k2s[srow] = part;
            bf16x8 p0, p1;
#pragma unroll
            for (int j = 0; j < 4; ++j) {
                p0[j]     = (short)f2bf(a[j]);
                p0[4 + j] = (short)f2bf(b[j]);
                p1[j]     = (short)f2bf(c[j]);
                p1[4 + j] = (short)f2bf(d[j]);
            }
            const int sw = (srow & 7) << 4;
            const int wa = srow * 128 + sc4 * 32;
            *(bf16x8*)(Kl + (wa ^ sw))        = p0;
            *(bf16x8*)(Kl + ((wa + 16) ^ sw)) = p1;
        }
        {
            const float* vp = Vg + hb + (size_t)(kt * KVB + 2 * vpr) * DIM + vd0;
            f32x4 a0 = *(const f32x4*)vp;
            f32x4 a1 = *(const f32x4*)(vp + 4);
            f32x4 b0 = *(const f32x4*)(vp + DIM);
            f32x4 b1 = *(const f32x4*)(vp + DIM + 4);
#pragma unroll
            for (int j = 0; j < 8; ++j) {
                const float lo = (j < 4) ? a0[j] : a1[j - 4];
                const float hi2 = (j < 4) ? b0[j] : b1[j - 4];
                const unsigned int pk = f2bf(lo) | (f2bf(hi2) << 16);
                const int d = vd0 + j;
                const int wa = d * 128 + vpr * 4;
                *(unsigned int*)(Vt + (wa ^ ((d & 7) << 4))) = pk;
            }
        }
        __syncthreads();

        f32x4 st[4];
#pragma unroll
        for (int f = 0; f < 4; ++f) st[f] = (f32x4){0.f, 0.f, 0.f, 0.f};
#pragma unroll
        for (int f = 0; f < 4; ++f) {
#pragma unroll
            for (int h = 0; h < 2; ++h) {
                const int ra = (f * 16 + lq) * 128 + h * 64 + g * 16;
                bf16x8 kf = *(const bf16x8*)(Kl + (ra ^ swq));
                st[f] = __builtin_amdgcn_mfma_f32_16x16x32_bf16(kf, qf[h], st[f], 0, 0, 0);
            }
        }

        float sc[4][4];
        float tmax = -INFINITY;
#pragma unroll
        for (int f = 0; f < 4; ++f) {
            const f32x4 k2v = *(const f32x4*)(k2s + f * 16 + g * 4);
#pragma unroll
            for (int r = 0; r < 4; ++r) {
                const float kk = k2v[r];
                const float sq = fmaxf(fmaf(-2.f, st[f][r], q2 + kk), 0.f);
                const float s  = (kk - sqrtf(sq)) * 0.0625f;
                sc[f][r] = s;
                tmax = fmaxf(tmax, s);
            }
        }
        tmax = fmaxf(tmax, __shfl_xor(tmax, 16));
        tmax = fmaxf(tmax, __shfl_xor(tmax, 32));
        const float nm    = fmaxf(m, tmax);
        const float scale = __expf(m - nm);
        m = nm;
        lsum *= scale;
#pragma unroll
        for (int i = 0; i < 4; ++i) {
            ofr[i][0] *= scale; ofr[i][1] *= scale;
            ofr[i][2] *= scale; ofr[i][3] *= scale;
        }
#pragma unroll
        for (int f = 0; f < 4; ++f) {
#pragma unroll
            for (int e = 0; e < 2; ++e) {
                const float p0 = __expf(sc[f][2 * e]     - m);
                const float p1 = __expf(sc[f][2 * e + 1] - m);
                lsum += p0 + p1;
                const unsigned int pk = f2bf(p0) | (f2bf(p1) << 16);
                const int pr = 8 * f + 2 * g + e;
                const int wa = lq * 128 + pr * 4;
                *(unsigned int*)(Pw + (wa ^ swq)) = pk;
            }
        }

        bf16x8 pf[2];
#pragma unroll
        for (int h = 0; h < 2; ++h) {
            const int ra = lq * 128 + h * 64 + g * 16;
            pf[h] = *(const bf16x8*)(Pw + (ra ^ swq));
        }
#pragma unroll
        for (int db = 0; db < 4; ++db) {
#pragma unroll
            for (int h = 0; h < 2; ++h) {
                const int ra = (db * 16 + lq) * 128 + h * 64 + g * 16;
                bf16x8 vf = *(const bf16x8*)(Vt + (ra ^ swq));
                ofr[db] = __builtin_amdgcn_mfma_f32_16x16x32_bf16(vf, pf[h], ofr[db], 0, 0, 0);
            }
        }
    }

    lsum += __shfl_xor(lsum, 16);
    lsum += __shfl_xor(lsum, 32);
    const float inv = 1.f / lsum;
    float* op = Og + hb + (size_t)q * DIM;
#pragma unroll
    for (int db = 0; db < 4; ++db) {
#pragma unroll
        for (int r = 0; r < 4; ++r) {
            op[db * 16 + g * 4 + r] = ofr[db][r] * inv;
        }
    }
}

extern "C" void kernel_launch(void* const* d_in, const int* in_sizes, int n_in,
                              void* d_out, int out_size, void* d_ws, size_t ws_size,
                              hipStream_t stream) {
    const float* Q = (const float*)d_in[0];
    const float* K = (const float*)d_in[1];
    const float* V = (const float*)d_in[2];
    float* O = (float*)d_out;

    const size_t KP_B = (size_t)NHEAD * NKT * TILE_B;    // 8 MB
    const size_t K2_B = (size_t)NHEAD * SEQ * 4;         // 256 KB
    const size_t need = 2 * KP_B + K2_B;

    if (ws_size >= need) {
        char*  Kp  = (char*)d_ws;
        char*  Vp  = Kp + KP_B;
        float* k2c = (float*)(Kp + 2 * KP_B);
        prep_kv<<<dim3(NKT, NHEAD), 256, 0, stream>>>(K, V, Kp, Vp, k2c);
        se_attn_main<<<dim3((SEQ / 64) * NHEAD), 256, 0, stream>>>(Q, Kp, Vp, k2c, O);
    } else {
        se_attn_mfma<<<dim3(SEQ / 64, NHEAD), 256, 0, stream>>>(Q, K, V, O);
    }
}